// Round 1
// 739.889 us; speedup vs baseline: 1.2457x; 1.2457x over previous
//
#include <hip/hip_runtime.h>
#include <cstdint>

typedef unsigned short u16;
typedef __attribute__((ext_vector_type(8))) __bf16 bf16x8;
typedef __attribute__((ext_vector_type(4))) float f32x4;

#define N_DIM 4096

__device__ __forceinline__ u16 f2bf(float f) {
    union { float f; unsigned u; } c; c.f = f;
    unsigned u = c.u;
    u += 0x7FFFu + ((u >> 16) & 1u);   // round-nearest-even
    return (u16)(u >> 16);
}

__device__ __forceinline__ void gl_lds16(const u16* g, u16* l) {
    __builtin_amdgcn_global_load_lds(
        (const __attribute__((address_space(1))) void*)g,
        (__attribute__((address_space(3))) void*)l, 16, 0, 0);
}

// ---------------------------------------------------------------------------
// Kernel 1: band table. bnd[n*9 + (off+4)] = M[n, n+off] (0 if out of range).
// ---------------------------------------------------------------------------
__global__ void band_kernel(const float* __restrict__ s,
                            const float* __restrict__ s_pre,
                            const float* __restrict__ gate,
                            float* __restrict__ bnd) {
    int n = blockIdx.x * blockDim.x + threadIdx.x;
    if (n >= N_DIM) return;
    float sig = 1.0f / (1.0f + __expf(-gate[0]));
    const int base[9] = {0, 4092, 8185, 12279, 16374, 20470, 24565, 28659, 32752};
    #pragma unroll
    for (int o = 0; o < 9; ++o) {
        int off = o - 4;
        int col = n + off;
        float val = 0.0f;
        if (col >= 0 && col < N_DIM) {
            int idx = (off >= 0) ? (base[o] + n) : (base[o] + n + off);
            val = s[idx] * sig;
        }
        if (off == 0) val += s_pre[n];
        bnd[n * 9 + o] = val;
    }
}

// ---------------------------------------------------------------------------
// Kernel 2: P[din, n] = sum_off bnd[n][off] * v[n+off, din], stored bf16,
// row-major [4096, 4096] (K=n contiguous). Tile transpose through LDS.
// ---------------------------------------------------------------------------
__global__ void band_combine_t(const float* __restrict__ v,
                               const float* __restrict__ bnd,
                               u16* __restrict__ P) {
    __shared__ float tile[32][33];
    int n0 = blockIdx.x * 32;
    int d0 = blockIdx.y * 32;
    int tx = threadIdx.x;   // 0..31  -> d (coalesced v reads)
    int ty = threadIdx.y;   // 0..7
    #pragma unroll
    for (int i = 0; i < 4; ++i) {
        int nl = ty + 8 * i;
        int n = n0 + nl;
        int d = d0 + tx;
        float acc = 0.0f;
        #pragma unroll
        for (int o = 0; o < 9; ++o) {
            int src = n + o - 4;
            float w = bnd[n * 9 + o];
            float vv = ((unsigned)src < (unsigned)N_DIM) ? v[(size_t)src * N_DIM + d] : 0.0f;
            acc += w * vv;
        }
        tile[nl][tx] = acc;
    }
    __syncthreads();
    #pragma unroll
    for (int i = 0; i < 4; ++i) {
        int dl = ty + 8 * i;
        P[(size_t)(d0 + dl) * N_DIM + (n0 + tx)] = f2bf(tile[tx][dl]);
    }
}

// ---------------------------------------------------------------------------
// Kernel 3: fp32 -> bf16 elementwise (float4 vectorized; nElem % 4 == 0)
// ---------------------------------------------------------------------------
__global__ void cvt_bf16(const float* __restrict__ in, u16* __restrict__ out, int nElem4) {
    int i = blockIdx.x * blockDim.x + threadIdx.x;
    if (i >= nElem4) return;
    float4 f = ((const float4*)in)[i];
    ushort4 o;
    o.x = f2bf(f.x); o.y = f2bf(f.y); o.z = f2bf(f.z); o.w = f2bf(f.w);
    ((ushort4*)out)[i] = o;
}

// ---------------------------------------------------------------------------
// 256x256x64 8-phase TN GEMM (m201 template, plain HIP).
//   C[m,n] = sum_k A[m,k]*B[n,k], A/B bf16 row-major, K % 128 == 0.
//   8 waves (2M x 4N), per-wave output 128x64 (8x4 frags of 16x16).
//   LDS: 2 buffers per operand, tile stored as 1024B subtiles (16 rows x 32 k),
//   st_16x32 XOR swizzle: byte ^= ((byte>>9)&1)<<5 within each subtile.
//   Staging: global_load_lds writes LINEAR (lane*16); source address is
//   inverse-swizzled so reads apply the same XOR (rule #21: both-sides).
//   Counted vmcnt(4) at phases 4/8 only; never drained in main loop.
// ---------------------------------------------------------------------------
#define BARRIER() __builtin_amdgcn_s_barrier()
#define LGKM0()   asm volatile("s_waitcnt lgkmcnt(0)" ::: "memory")
#define VMC(n)    asm volatile("s_waitcnt vmcnt(" #n ")" ::: "memory")

#define MFMA_Q(QM, QN) do {                                                   \
    __builtin_amdgcn_s_setprio(1);                                            \
    _Pragma("unroll")                                                         \
    for (int k_ = 0; k_ < 2; ++k_)                                            \
      _Pragma("unroll")                                                       \
      for (int i_ = 0; i_ < 4; ++i_)                                          \
        _Pragma("unroll")                                                     \
        for (int j_ = 0; j_ < 2; ++j_)                                        \
          acc[(QM)*4 + i_][(QN)*2 + j_] =                                     \
            __builtin_amdgcn_mfma_f32_16x16x32_bf16(                          \
              aR[i_][k_], bR[(QN)*2 + j_][k_],                                \
              acc[(QM)*4 + i_][(QN)*2 + j_], 0, 0, 0);                        \
    __builtin_amdgcn_s_setprio(0);                                            \
  } while (0)

template <bool OUT_BF16>
__global__ __launch_bounds__(512, 2)
void gemm_tn8(const u16* __restrict__ A, const u16* __restrict__ B,
              float* __restrict__ Cf, u16* __restrict__ Cb,
              int M, int N, int K) {
    __shared__ __align__(16) u16 As[2][16384];   // 2 x 32KB
    __shared__ __align__(16) u16 Bs[2][16384];   // 2 x 32KB  -> 128 KiB total

    const int tid = threadIdx.x;
    const int l   = tid & 63;
    const int w   = tid >> 6;        // 0..7
    const int wm  = w >> 2;          // 0..1
    const int wn  = w & 3;           // 0..3

    // T1: bijective XCD-aware block swizzle on flattened id (nwg % 8 == 0 here)
    const int nbx = gridDim.x;
    const int nwg = nbx * gridDim.y;
    int lid = blockIdx.y * nbx + blockIdx.x;
    if ((nwg & 7) == 0) lid = (lid & 7) * (nwg >> 3) + (lid >> 3);
    const long m0 = (long)(lid / nbx) * 256;
    const long n0 = (long)(lid % nbx) * 256;

    const u16* Ab = A + m0 * (long)K;
    const u16* Bb = B + n0 * (long)K;

    // ---- staging thread-constants -------------------------------------
    // One wave-instruction fills one 1024B subtile linearly (lane -> l*16).
    // Inverse-swizzled source: lane l loads logical 16B-chunk (l<32 ? l : l^2).
    const int lin16 = (l < 32) ? l : (l ^ 2);
    const int sr = lin16 >> 2;            // row in subtile 0..15
    const int sc = (lin16 & 3) * 8;       // k element offset 0/8/16/24
    const int s0 = w;                     // line-0 subtile (0..7)
    const int s1 = 8 + w;                 // line-1 subtile (8..15)
    const int g0 = ((s0 >> 1) * 16 + sr) * K + (s0 & 1) * 32 + sc;
    const int g1 = ((s1 >> 1) * 16 + sr) * K + (s1 & 1) * 32 + sc;
    const int d0 = s0 * 512 + l * 8;      // u16 offset inside half-region
    const int d1 = s1 * 512 + l * 8;

    // ---- fragment-read thread-constant (swizzled ds_read address) ------
    // logical byte = (row&15)*64 + (l>>4)*16 ; XOR bit5 with bit9 (= row>=8)
    const int foff = (((((l & 15) << 6) + ((l >> 4) << 4)) ^ (((l >> 3) & 1) << 5)) >> 1);
    const int abase = wm * 8192;          // u16: wave's A subtile region
    const int bbase = wn * 4096;          // u16: wave's B subtile region

    f32x4 acc[8][4];
    #pragma unroll
    for (int i = 0; i < 8; ++i)
        #pragma unroll
        for (int j = 0; j < 4; ++j)
            acc[i][j] = (f32x4){0.f, 0.f, 0.f, 0.f};

    bf16x8 aR[4][2], bR[4][2];

    auto stageA = [&](int buf, int t, int h) {
        const u16* g = Ab + (long)h * 128 * K + (long)t * 64;
        u16* lb = &As[buf][h * 8192];
        gl_lds16(g + g0, lb + d0);
        gl_lds16(g + g1, lb + d1);
    };
    auto stageB = [&](int buf, int t, int h) {
        const u16* g = Bb + (long)h * 128 * K + (long)t * 64;
        u16* lb = &Bs[buf][h * 8192];
        gl_lds16(g + g0, lb + d0);
        gl_lds16(g + g1, lb + d1);
    };
    auto loadA4 = [&](int buf, int fmBase) {   // aR[0..3][0..1] <- fm = fmBase..+3
        #pragma unroll
        for (int i = 0; i < 4; ++i)
            #pragma unroll
            for (int ks = 0; ks < 2; ++ks)
                aR[i][ks] = *(const bf16x8*)&As[buf][abase + (fmBase + i) * 1024 + ks * 512 + foff];
    };
    auto loadB2 = [&](int buf, int fnBase) {   // bR[fnBase..+1][0..1]
        #pragma unroll
        for (int i = 0; i < 2; ++i)
            #pragma unroll
            for (int ks = 0; ks < 2; ++ks)
                bR[fnBase + i][ks] = *(const bf16x8*)&Bs[buf][bbase + (fnBase + i) * 1024 + ks * 512 + foff];
    };

    const int NT = K >> 6;                 // 64-wide K tiles (even; K%128==0)

    // ---- prologue: tile0 -> buf0 (full), tile1 B-halves -> buf1 --------
    stageA(0, 0, 0); stageA(0, 0, 1);
    stageB(0, 0, 0); stageB(0, 0, 1);
    stageB(1, 1, 0); stageB(1, 1, 1);
    VMC(4);                                // tile0 fully landed; B(1) in flight
    BARRIER();

    // ---- main loop: 2 K-tiles per iteration, 8 phases ------------------
    for (int it = 0; it < (NT >> 1); ++it) {
        const int kt = it * 2;
        const int t2 = (kt + 2 < NT) ? kt + 2 : NT - 1;   // clamp: dead data,
        const int t3 = (kt + 3 < NT) ? kt + 3 : NT - 1;   // keeps vmcnt exact

        // P1: Q(0,0) of buf0 | stage A-lo(kt+1)->buf1
        loadA4(0, 0); loadB2(0, 0);
        stageA(1, kt + 1, 0);
        BARRIER(); LGKM0();
        MFMA_Q(0, 0);
        BARRIER();

        // P2: Q(0,1) | stage A-hi(kt+1)->buf1
        loadB2(0, 2);
        stageA(1, kt + 1, 1);
        BARRIER(); LGKM0();
        MFMA_Q(0, 1);
        BARRIER();

        // P3: Q(1,0) | stage B-lo(kt+2)->buf0  (buf0.B reads done after P2)
        loadA4(0, 4);
        stageB(0, t2, 0);
        BARRIER(); LGKM0();
        MFMA_Q(1, 0);
        BARRIER();

        // P4: Q(1,1) | stage B-hi(kt+2)->buf0 ; counted wait: buf1 complete
        stageB(0, t2, 1);
        VMC(4);
        BARRIER(); LGKM0();
        MFMA_Q(1, 1);
        BARRIER();

        // P5: Q(0,0) of buf1 | stage A-lo(kt+2)->buf0 (buf0.A reads done after P3)
        loadA4(1, 0); loadB2(1, 0);
        stageA(0, t2, 0);
        BARRIER(); LGKM0();
        MFMA_Q(0, 0);
        BARRIER();

        // P6: Q(0,1) | stage A-hi(kt+2)->buf0
        loadB2(1, 2);
        stageA(0, t2, 1);
        BARRIER(); LGKM0();
        MFMA_Q(0, 1);
        BARRIER();

        // P7: Q(1,0) | stage B-lo(kt+3)->buf1 (buf1.B reads done after P6)
        loadA4(1, 4);
        stageB(1, t3, 0);
        BARRIER(); LGKM0();
        MFMA_Q(1, 0);
        BARRIER();

        // P8: Q(1,1) | stage B-hi(kt+3)->buf1 ; counted wait: buf0 complete
        stageB(1, t3, 1);
        VMC(4);
        BARRIER(); LGKM0();
        MFMA_Q(1, 1);
        BARRIER();
    }

    VMC(0);   // drain dead prefetches before endpgm

    // ---- epilogue: D layout col = lane&15, row = (lane>>4)*4 + reg [m89]
    const int cn = l & 15;
    const int rg = l >> 4;
    #pragma unroll
    for (int fm = 0; fm < 8; ++fm) {
        #pragma unroll
        for (int fn = 0; fn < 4; ++fn) {
            const long mb = m0 + wm * 128 + fm * 16 + rg * 4;
            const long nn = n0 + wn * 64 + fn * 16 + cn;
            #pragma unroll
            for (int r = 0; r < 4; ++r) {
                const long off = (mb + r) * N + nn;
                if (OUT_BF16) Cb[off] = f2bf(acc[fm][fn][r]);
                else          Cf[off] = acc[fm][fn][r];
            }
        }
    }
}

// ---------------------------------------------------------------------------
// out = x @ ((M v)^T u^T)  computed as:
//   bnd   = band table of M                       (tiny)
//   P     = (M v)^T   bf16  [D_IN, N]             (banded combine + transpose)
//   Ubf   = bf16(u)         [D_OUT, N]
//   Xbf   = bf16(x)         [B*S, D_IN]
//   Wt    = weight^T = u M v = GEMM_TN(Ubf, P)    [D_OUT, D_IN] bf16
//   out   = GEMM_TN(Xbf, Wt)                      [B*S, D_OUT] fp32
// ---------------------------------------------------------------------------
extern "C" void kernel_launch(void* const* d_in, const int* in_sizes, int n_in,
                              void* d_out, int out_size, void* d_ws, size_t ws_size,
                              hipStream_t stream) {
    const float* x     = (const float*)d_in[0];   // [4, 2048, 4096]
    const float* u     = (const float*)d_in[1];   // [4096, 4096]
    const float* v     = (const float*)d_in[2];   // [4096, 4096]
    const float* s_pre = (const float*)d_in[3];   // [4096]
    const float* s     = (const float*)d_in[4];   // [36844]
    const float* gate  = (const float*)d_in[5];   // [1]
    float* out = (float*)d_out;                    // [8192, 4096]

    const int BS = 8192;        // 4*2048
    const size_t NN = (size_t)N_DIM * N_DIM;       // 16777216

    char* ws = (char*)d_ws;
    float* bnd = (float*)ws;                                   // 147 KB
    u16*   P   = (u16*)(ws + (1 << 18));                       // 32 MB
    u16*   Ubf = (u16*)(ws + (1 << 18) + NN * 2);              // 32 MB
    u16*   Wt  = (u16*)(ws + (1 << 18) + NN * 4);              // 32 MB
    u16*   Xbf = (u16*)(ws + (1 << 18) + NN * 6);              // 64 MB

    // 1. band table
    band_kernel<<<16, 256, 0, stream>>>(s, s_pre, gate, bnd);

    // 2. P = (M v)^T in bf16
    band_combine_t<<<dim3(128, 128), dim3(32, 8), 0, stream>>>(v, bnd, P);

    // 3. bf16 casts
    cvt_bf16<<<(int)(NN / 4 / 256), 256, 0, stream>>>(u, Ubf, (int)(NN / 4));
    cvt_bf16<<<(int)((size_t)BS * N_DIM / 4 / 256), 256, 0, stream>>>(
        x, Xbf, (int)((size_t)BS * N_DIM / 4));

    // 4. Wt = Ubf @ P^T   [4096 x 4096], bf16 output
    gemm_tn8<true><<<dim3(N_DIM / 256, N_DIM / 256), 512, 0, stream>>>(
        Ubf, P, nullptr, Wt, N_DIM, N_DIM, N_DIM);

    // 5. out = Xbf @ Wt^T  [8192 x 4096], fp32 output
    gemm_tn8<false><<<dim3(N_DIM / 256, BS / 256), 512, 0, stream>>>(
        Xbf, Wt, out, nullptr, BS, N_DIM, N_DIM);
}